// Round 3
// baseline (667.788 us; speedup 1.0000x reference)
//
#include <hip/hip_runtime.h>
#include <hip/hip_bf16.h>
#include <cstdint>

// SpatialAttentionModule: x[4,256,64,64] fp32; q=Wq x, k=Wk x, v=Wv x (1x1 conv);
// energy = q^T k per batch (N=4096), softmax over j, out = gamma * (v @ attn^T) + x.
//
// Round-3: k_attn rewritten as single-pass ONLINE softmax (phase-1 exact-max
// pass removed) with DOUBLE-BUFFERED LDS staging (load t+1 -> regs, compute t,
// store regs -> other buffer, one barrier per tile). R2 was serialization-bound:
// MfmaUtil 16.7%, VALUBusy 16.6%, HBM 6%, occupancy = 1 block/CU with a full
// stage->sync->compute->sync serialization per tile.
// Precision: split-bf16 (hi|lo along K=512) on the whole Q/K/V-projection path,
// p<=1 online so bf16-P rounding identical in character to R2 (absmax 0.1016).
// MFMA layouts (HW-verified, learn_hip m89/m91):
//   A[m=lane&15][k=quad*8+j], B[k=quad*8+j][n=lane&15], C/D: col=lane&15, row=quad*4+reg.

#define C_DIM 256
#define CK 512          // split contraction dim (hi 0..255 | lo 256..511)
#define N_DIM 4096
#define B_DIM 4

typedef short bf16x8 __attribute__((ext_vector_type(8)));
typedef float f32x4  __attribute__((ext_vector_type(4)));

__device__ __forceinline__ unsigned short f2bf(float f) {
  union { float f; unsigned u; } v; v.f = f;
  unsigned r = v.u + 0x7fffu + ((v.u >> 16) & 1u);   // round-to-nearest-even
  return (unsigned short)(r >> 16);
}
__device__ __forceinline__ float bf2f(unsigned short h) {
  union { unsigned u; float f; } v; v.u = ((unsigned)h) << 16;
  return v.f;
}

// ---------------- prep: transpose-cast x -> xs split-bf16 [B*N][512] ----------------
__global__ __launch_bounds__(256) void k_prep_xs(const float* __restrict__ x,
                                                 unsigned short* __restrict__ xs) {
  __shared__ float tile[64][65];
  const int b = blockIdx.z, nb = blockIdx.x * 64, cb = blockIdx.y * 64;
  const float* xb = x + (size_t)b * C_DIM * N_DIM;
  for (int i = threadIdx.x; i < 64 * 64; i += 256) {
    int c = i >> 6, n = i & 63;
    tile[c][n] = xb[(size_t)(cb + c) * N_DIM + nb + n];
  }
  __syncthreads();
  unsigned short* xsb = xs + (size_t)b * N_DIM * CK;
  for (int i = threadIdx.x; i < 64 * 64; i += 256) {
    int n = i >> 6, c = i & 63;
    float v = tile[c][n];
    unsigned short hi = f2bf(v);
    unsigned short lo = f2bf(v - bf2f(hi));
    unsigned short* row = xsb + (size_t)(nb + n) * CK + cb + c;
    row[0] = hi;
    row[256] = lo;
  }
}

// ---------------- prep: split-cast 3 weight matrices -> Ws [3*256][512] ----------------
__global__ __launch_bounds__(256) void k_cast_ws(const float* __restrict__ Wq,
                                                 const float* __restrict__ Wk,
                                                 const float* __restrict__ Wv,
                                                 unsigned short* __restrict__ Ws) {
  int i = blockIdx.x * 256 + threadIdx.x;          // 0 .. 3*65536-1
  int sel = i >> 16, j = i & 65535;
  int o = j >> 8, c = j & 255;
  const float* s = (sel == 0) ? Wq : (sel == 1) ? Wk : Wv;
  float v = s[j];
  unsigned short hi = f2bf(v);
  unsigned short lo = f2bf(v - bf2f(hi));
  unsigned short* row = Ws + (size_t)(sel * 256 + o) * CK + c;
  row[0] = hi;
  row[256] = lo;
}

// ---------------- QKV projection GEMMs (K=512 split) ----------------
__global__ __launch_bounds__(256) void k_proj(const unsigned short* __restrict__ xs,
                                              const unsigned short* __restrict__ Ws,
                                              const float* __restrict__ bq,
                                              const float* __restrict__ bk,
                                              const float* __restrict__ bv,
                                              unsigned short* __restrict__ Qs,
                                              unsigned short* __restrict__ Ks,
                                              unsigned short* __restrict__ Vc) {
  const int z = blockIdx.y;
  const int w = threadIdx.x >> 6, lane = threadIdx.x & 63;
  const int quad = lane >> 4, li = lane & 15;
  const unsigned short* W = Ws + (size_t)z * 256 * CK;
  const float* bias = (z == 0) ? bq : (z == 1) ? bk : bv;

  if (z < 2) {
    unsigned short* out = (z == 0) ? Qs : Ks;
    const int g0 = (blockIdx.x * 4 + w) * 16;
    bf16x8 a[16];
    const unsigned short* arow = xs + (size_t)(g0 + li) * CK + quad * 8;
#pragma unroll
    for (int kf = 0; kf < 16; kf++) a[kf] = *(const bf16x8*)(arow + kf * 32);
    for (int ot = 0; ot < 16; ot++) {
      f32x4 acc = {0.f, 0.f, 0.f, 0.f};
      const unsigned short* brow = W + (size_t)(ot * 16 + li) * CK + quad * 8;
#pragma unroll
      for (int kf = 0; kf < 16; kf++) {
        bf16x8 bf = *(const bf16x8*)(brow + kf * 32);
        acc = __builtin_amdgcn_mfma_f32_16x16x32_bf16(a[kf], bf, acc, 0, 0, 0);
      }
      float bb = bias[ot * 16 + li];
      unsigned short* orow = out + (size_t)g0 * CK + ot * 16 + li;
#pragma unroll
      for (int r = 0; r < 4; r++) {
        float val = acc[r] + bb;
        unsigned short hi = f2bf(val);
        unsigned short lo = f2bf(val - bf2f(hi));
        orow[(size_t)(quad * 4 + r) * CK] = hi;
        orow[(size_t)(quad * 4 + r) * CK + 256] = lo;
      }
    }
  } else {
    const int t = blockIdx.x * 4 + w;
    const int b = t >> 8, j0 = (t & 255) * 16;
    bf16x8 bfr[16];
    const unsigned short* brow = xs + (size_t)(b * N_DIM + j0 + li) * CK + quad * 8;
#pragma unroll
    for (int kf = 0; kf < 16; kf++) bfr[kf] = *(const bf16x8*)(brow + kf * 32);
    for (int ot = 0; ot < 16; ot++) {
      f32x4 acc = {0.f, 0.f, 0.f, 0.f};
      const unsigned short* arow = W + (size_t)(ot * 16 + li) * CK + quad * 8;
#pragma unroll
      for (int kf = 0; kf < 16; kf++) {
        bf16x8 af = *(const bf16x8*)(arow + kf * 32);
        acc = __builtin_amdgcn_mfma_f32_16x16x32_bf16(af, bfr[kf], acc, 0, 0, 0);
      }
      unsigned short* obase = Vc + ((size_t)(b * C_DIM + ot * 16 + quad * 4)) * N_DIM + j0 + li;
#pragma unroll
      for (int r = 0; r < 4; r++) {
        float bb = bias[ot * 16 + quad * 4 + r];
        obase[(size_t)r * N_DIM] = f2bf(acc[r] + bb);
      }
    }
  }
}

// ---------------- fused attention: single-pass online softmax, double-buffered ----------------
// grid (64,4): x = 64-query block, y = batch. 4 waves x 16 query-cols each.
// Per tile (JT=32 keys): S^T via MFMA (K=512 split), online m/rescale, P bf16
// -> LDS, O^T += V * P^T. K/V double-buffered: load t+1 -> regs, compute t,
// store regs -> buf^1, one barrier.
#define JT 32
#define NT (N_DIM / JT)    // 128 tiles
#define KSTR 520   // K LDS row: 512 data + 8 pad ushorts (1040 B)
#define VSTR 40    // V LDS row: 32 data + 8 pad
#define PSTR 40
// LDS ushorts: K0 16640 | K1 16640 | V0 10240 | V1 10240 | P 4*16*40=2560 -> 56320 (112.6 KB)
#define K0_OFF 0
#define K1_OFF 16640
#define V0_OFF 33280
#define V1_OFF 43520
#define P_OFF  53760

__global__ __launch_bounds__(256, 1) void k_attn(const unsigned short* __restrict__ Qs,
                                                 const unsigned short* __restrict__ Ks,
                                                 const unsigned short* __restrict__ Vc,
                                                 const float* __restrict__ x,
                                                 const float* __restrict__ gamma_p,
                                                 float* __restrict__ out) {
  __shared__ __align__(16) unsigned short smem[56320];
  const int b = blockIdx.y;
  const int tid = threadIdx.x;
  const int w = tid >> 6, lane = tid & 63;
  const int quad = lane >> 4, li = lane & 15;
  const int ibase = blockIdx.x * 64 + w * 16;

  // Q fragments (B-operand: n=i query col, k over 512 split channels)
  bf16x8 qf[16];
  {
    const unsigned short* qrow = Qs + (size_t)(b * N_DIM + ibase + li) * CK + quad * 8;
#pragma unroll
    for (int kf = 0; kf < 16; kf++) qf[kf] = *(const bf16x8*)(qrow + kf * 32);
  }
  const unsigned short* Kb = Ks + (size_t)b * N_DIM * CK;
  const unsigned short* Vb = Vc + (size_t)b * C_DIM * N_DIM;

  unsigned short* Kbuf0 = smem + K0_OFF;
  unsigned short* Kbuf1 = smem + K1_OFF;
  unsigned short* Vbuf0 = smem + V0_OFF;
  unsigned short* Vbuf1 = smem + V1_OFF;
  unsigned short* P_lds = smem + P_OFF + w * 16 * PSTR;   // per-wave [16][PSTR]

  // per-thread staging coordinates
  const int kcol = (tid & 63) * 8;   // K: thread covers rows {it*4+w}, 16B at col kcol
  const int vrow = tid >> 2;         // V: thread covers rows {it*64? no: vrow}, see below
  const int vcol = (tid & 3) * 8;    // V: 4 threads x 16B cover the 32-key row

  const float LOG2E = 1.4426950408889634f;
  float m = -3.0e38f;
  float l = 0.0f;
  f32x4 acc[16];
#pragma unroll
  for (int ct = 0; ct < 16; ct++) acc[ct] = (f32x4){0.f, 0.f, 0.f, 0.f};

  float4 kr[8];
  float4 vr[4];

  // prologue: stage tile 0 into buf0
  {
#pragma unroll
    for (int it = 0; it < 8; it++)
      kr[it] = *(const float4*)(Kb + (size_t)(it * 4 + w) * CK + kcol);
#pragma unroll
    for (int it = 0; it < 4; it++)
      vr[it] = *(const float4*)(Vb + (size_t)(it * 64 + vrow) * N_DIM + vcol);
#pragma unroll
    for (int it = 0; it < 8; it++)
      *(float4*)(Kbuf0 + (it * 4 + w) * KSTR + kcol) = kr[it];
#pragma unroll
    for (int it = 0; it < 4; it++)
      *(float4*)(Vbuf0 + (it * 64 + vrow) * VSTR + vcol) = vr[it];
  }
  __syncthreads();

  for (int t = 0; t < NT; t++) {
    const unsigned short* K_lds = (t & 1) ? Kbuf1 : Kbuf0;
    const unsigned short* V_lds = (t & 1) ? Vbuf1 : Vbuf0;
    unsigned short* Kn = (t & 1) ? Kbuf0 : Kbuf1;
    unsigned short* Vn = (t & 1) ? Vbuf0 : Vbuf1;

    // issue next tile's global loads (latency hidden by compute below)
    if (t + 1 < NT) {
      const int jt = (t + 1) * JT;
#pragma unroll
      for (int it = 0; it < 8; it++)
        kr[it] = *(const float4*)(Kb + (size_t)(jt + it * 4 + w) * CK + kcol);
#pragma unroll
      for (int it = 0; it < 4; it++)
        vr[it] = *(const float4*)(Vb + (size_t)(it * 64 + vrow) * N_DIM + jt + vcol);
    }

    // ---- S^T tiles: rows j (quad*4+reg), cols i (lane&15); K=512 split ----
    f32x4 s0 = {0.f, 0.f, 0.f, 0.f}, s1 = {0.f, 0.f, 0.f, 0.f};
    {
      const unsigned short* krow0 = K_lds + li * KSTR + quad * 8;
      const unsigned short* krow1 = K_lds + (16 + li) * KSTR + quad * 8;
#pragma unroll
      for (int kf = 0; kf < 16; kf++) {
        bf16x8 k0 = *(const bf16x8*)(krow0 + kf * 32);
        s0 = __builtin_amdgcn_mfma_f32_16x16x32_bf16(k0, qf[kf], s0, 0, 0, 0);
      }
#pragma unroll
      for (int kf = 0; kf < 16; kf++) {
        bf16x8 k1 = *(const bf16x8*)(krow1 + kf * 32);
        s1 = __builtin_amdgcn_mfma_f32_16x16x32_bf16(k1, qf[kf], s1, 0, 0, 0);
      }
    }

    // ---- online softmax update (per query col li) ----
    float tm = fmaxf(fmaxf(fmaxf(s0[0], s0[1]), fmaxf(s0[2], s0[3])),
                     fmaxf(fmaxf(s1[0], s1[1]), fmaxf(s1[2], s1[3])));
    tm = fmaxf(tm, __shfl_xor(tm, 16));
    tm = fmaxf(tm, __shfl_xor(tm, 32));
    float new_m = fmaxf(m, tm);
    float alpha = exp2f((m - new_m) * LOG2E);
    m = new_m;
    l *= alpha;
#pragma unroll
    for (int ct = 0; ct < 16; ct++) {
      acc[ct][0] *= alpha; acc[ct][1] *= alpha;
      acc[ct][2] *= alpha; acc[ct][3] *= alpha;
    }
    {
      float p0 = exp2f((s0[0] - m) * LOG2E), p1 = exp2f((s0[1] - m) * LOG2E);
      float p2 = exp2f((s0[2] - m) * LOG2E), p3 = exp2f((s0[3] - m) * LOG2E);
      unsigned short h0 = f2bf(p0), h1 = f2bf(p1), h2 = f2bf(p2), h3 = f2bf(p3);
      l += (bf2f(h0) + bf2f(h1)) + (bf2f(h2) + bf2f(h3));
      *(uint2*)(P_lds + li * PSTR + quad * 4) =
          make_uint2((unsigned)h0 | ((unsigned)h1 << 16), (unsigned)h2 | ((unsigned)h3 << 16));
      float q0 = exp2f((s1[0] - m) * LOG2E), q1 = exp2f((s1[1] - m) * LOG2E);
      float q2 = exp2f((s1[2] - m) * LOG2E), q3 = exp2f((s1[3] - m) * LOG2E);
      unsigned short g0 = f2bf(q0), g1 = f2bf(q1), g2 = f2bf(q2), g3 = f2bf(q3);
      l += (bf2f(g0) + bf2f(g1)) + (bf2f(g2) + bf2f(g3));
      *(uint2*)(P_lds + li * PSTR + 16 + quad * 4) =
          make_uint2((unsigned)g0 | ((unsigned)g1 << 16), (unsigned)g2 | ((unsigned)g3 << 16));
    }

    // ---- PV: O^T[c][i] += V[c][j] P^T[j][i] ----
    bf16x8 pf = *(const bf16x8*)(P_lds + li * PSTR + quad * 8);
#pragma unroll
    for (int ct = 0; ct < 16; ct++) {
      bf16x8 vf = *(const bf16x8*)(V_lds + (ct * 16 + li) * VSTR + quad * 8);
      acc[ct] = __builtin_amdgcn_mfma_f32_16x16x32_bf16(vf, pf, acc[ct], 0, 0, 0);
    }

    // ---- stage next tile regs -> other buffer ----
    if (t + 1 < NT) {
#pragma unroll
      for (int it = 0; it < 8; it++)
        *(float4*)(Kn + (it * 4 + w) * KSTR + kcol) = kr[it];
#pragma unroll
      for (int it = 0; it < 4; it++)
        *(float4*)(Vn + (it * 64 + vrow) * VSTR + vcol) = vr[it];
    }
    __syncthreads();
  }

  l += __shfl_xor(l, 16);
  l += __shfl_xor(l, 32);           // all lanes: sum for query col i = lane&15
  const float scale = gamma_p[0] / l;

  const float* xb = x + (size_t)b * C_DIM * N_DIM;
  float* ob = out + (size_t)b * C_DIM * N_DIM;
  const int icol = ibase + li;
#pragma unroll
  for (int ct = 0; ct < 16; ct++) {
#pragma unroll
    for (int r = 0; r < 4; r++) {
      size_t off = (size_t)(ct * 16 + quad * 4 + r) * N_DIM + icol;
      ob[off] = acc[ct][r] * scale + xb[off];
    }
  }
}

extern "C" void kernel_launch(void* const* d_in, const int* in_sizes, int n_in,
                              void* d_out, int out_size, void* d_ws, size_t ws_size,
                              hipStream_t stream) {
  const float* x     = (const float*)d_in[0];
  const float* Wq    = (const float*)d_in[1];
  const float* bq    = (const float*)d_in[2];
  const float* Wk    = (const float*)d_in[3];
  const float* bk    = (const float*)d_in[4];
  const float* Wv    = (const float*)d_in[5];
  const float* bv    = (const float*)d_in[6];
  const float* gamma = (const float*)d_in[7];
  float* out = (float*)d_out;

  // workspace: xs 16MB | Qs 16MB | Ks 16MB | V 8MB | Ws 768KB  (~56.75 MB)
  char* ws = (char*)d_ws;
  unsigned short* xs = (unsigned short*)(ws);
  unsigned short* Qs = (unsigned short*)(ws + (size_t)16 * 1024 * 1024);
  unsigned short* Ksp= (unsigned short*)(ws + (size_t)32 * 1024 * 1024);
  unsigned short* Vc = (unsigned short*)(ws + (size_t)48 * 1024 * 1024);
  unsigned short* Wsp= (unsigned short*)(ws + (size_t)56 * 1024 * 1024);

  k_prep_xs<<<dim3(64, 4, 4), 256, 0, stream>>>(x, xs);
  k_cast_ws<<<dim3(768), 256, 0, stream>>>(Wq, Wk, Wv, Wsp);
  k_proj<<<dim3(256, 3), 256, 0, stream>>>(xs, Wsp, bq, bk, bv, Qs, Ksp, Vc);
  k_attn<<<dim3(64, 4), 256, 0, stream>>>(Qs, Ksp, Vc, x, gamma, out);
}

// Round 4
// 299.547 us; speedup vs baseline: 2.2293x; 2.2293x over previous
//
#include <hip/hip_runtime.h>
#include <hip/hip_bf16.h>
#include <cstdint>

// SpatialAttentionModule: x[4,256,64,64] fp32; q=Wq x, k=Wk x, v=Wv x (1x1 conv);
// energy = q^T k per batch (N=4096), softmax over j, out = gamma*(v@attn^T) + x.
//
// Round-4: full fp16 pipeline (mfma_f32_16x16x32_f16). fp16 mantissa (2^-11)
// is 8x finer than bf16 -> absmax ~0.109/8 ~ 0.015 (R2's "split-bf16 concat"
// missed the hi*lo cross terms, so it was no better than plain bf16).
// K=256 halves the S-path LDS/MFMA cost vs R2's split-512.
// k_attn: single-pass online softmax, JT=64 key tiles, double-buffered
// global_load_lds DMA staging (no ds_write from waves - R3's conflict source),
// bank-even LDS layouts via inter-span padding (1024B DMA span + 32B pad).
// MFMA layouts (HW-verified, learn_hip m89/m91, dtype-independent):
//   A[m=lane&15][k=quad*8+j], B[k=quad*8+j][n=lane&15], C/D: col=lane&15, row=quad*4+reg.

#define C_DIM 256
#define N_DIM 4096
#define B_DIM 4

typedef _Float16 f16;
typedef f16 f16x8 __attribute__((ext_vector_type(8)));
typedef f16 f16x4 __attribute__((ext_vector_type(4)));
typedef float f32x4 __attribute__((ext_vector_type(4)));

__device__ __forceinline__ void dma16(const f16* g, f16* l) {
  __builtin_amdgcn_global_load_lds(
      (const __attribute__((address_space(1))) unsigned int*)g,
      (__attribute__((address_space(3))) unsigned int*)l, 16, 0, 0);
}

// ---------------- prep: transpose-cast x -> xs fp16 [B*N][256] ----------------
__global__ __launch_bounds__(256) void k_prep_xs(const float* __restrict__ x,
                                                 f16* __restrict__ xs) {
  __shared__ float tile[64][65];
  const int b = blockIdx.z, nb = blockIdx.x * 64, cb = blockIdx.y * 64;
  const float* xb = x + (size_t)b * C_DIM * N_DIM;
  for (int i = threadIdx.x; i < 64 * 64; i += 256) {
    int c = i >> 6, n = i & 63;
    tile[c][n] = xb[(size_t)(cb + c) * N_DIM + nb + n];
  }
  __syncthreads();
  f16* xsb = xs + (size_t)b * N_DIM * C_DIM;
  for (int i = threadIdx.x; i < 64 * 64; i += 256) {
    int n = i >> 6, c = i & 63;
    xsb[(size_t)(nb + n) * C_DIM + cb + c] = (f16)tile[c][n];
  }
}

// ---------------- prep: cast 3 weight matrices -> fp16 [3*256][256] ----------------
__global__ __launch_bounds__(256) void k_cast_w(const float* __restrict__ Wq,
                                                const float* __restrict__ Wk,
                                                const float* __restrict__ Wv,
                                                f16* __restrict__ Wh) {
  int i = blockIdx.x * 256 + threadIdx.x;          // 0 .. 3*65536-1
  int sel = i >> 16, j = i & 65535;
  const float* s = (sel == 0) ? Wq : (sel == 1) ? Wk : Wv;
  Wh[i] = (f16)s[j];
}

// ---------------- QKV projection GEMMs (fp16, K=256) ----------------
// z=0: Qh[g][o] = sum_c Wq[o][c] x[g][c] + bq[o]   (layout [B*N][256])
// z=1: Kh same; z=2: Vh[b][o][j] (layout [B*C][N])
__global__ __launch_bounds__(256) void k_proj(const f16* __restrict__ xs,
                                              const f16* __restrict__ Wh,
                                              const float* __restrict__ bq,
                                              const float* __restrict__ bk,
                                              const float* __restrict__ bv,
                                              f16* __restrict__ Qh,
                                              f16* __restrict__ Kh,
                                              f16* __restrict__ Vh) {
  const int z = blockIdx.y;
  const int w = threadIdx.x >> 6, lane = threadIdx.x & 63;
  const int quad = lane >> 4, li = lane & 15;
  const f16* W = Wh + (size_t)z * 65536;
  const float* bias = (z == 0) ? bq : (z == 1) ? bk : bv;

  if (z < 2) {
    f16* out = (z == 0) ? Qh : Kh;
    const int g0 = (blockIdx.x * 4 + w) * 16;
    f16x8 a[8];
    const f16* arow = xs + (size_t)(g0 + li) * C_DIM + quad * 8;
#pragma unroll
    for (int kf = 0; kf < 8; kf++) a[kf] = *(const f16x8*)(arow + kf * 32);
    for (int ot = 0; ot < 16; ot++) {
      f32x4 acc = {0.f, 0.f, 0.f, 0.f};
      const f16* brow = W + (size_t)(ot * 16 + li) * C_DIM + quad * 8;
#pragma unroll
      for (int kf = 0; kf < 8; kf++) {
        f16x8 bf = *(const f16x8*)(brow + kf * 32);
        acc = __builtin_amdgcn_mfma_f32_16x16x32_f16(a[kf], bf, acc, 0, 0, 0);
      }
      float bb = bias[ot * 16 + li];
      f16* orow = out + (size_t)g0 * C_DIM + ot * 16 + li;
#pragma unroll
      for (int r = 0; r < 4; r++)
        orow[(size_t)(quad * 4 + r) * C_DIM] = (f16)(acc[r] + bb);
    }
  } else {
    const int t = blockIdx.x * 4 + w;
    const int b = t >> 8, j0 = (t & 255) * 16;
    f16x8 bfr[8];
    const f16* brow = xs + (size_t)(b * N_DIM + j0 + li) * C_DIM + quad * 8;
#pragma unroll
    for (int kf = 0; kf < 8; kf++) bfr[kf] = *(const f16x8*)(brow + kf * 32);
    for (int ot = 0; ot < 16; ot++) {
      f32x4 acc = {0.f, 0.f, 0.f, 0.f};
      const f16* arow = W + (size_t)(ot * 16 + li) * C_DIM + quad * 8;
#pragma unroll
      for (int kf = 0; kf < 8; kf++) {
        f16x8 af = *(const f16x8*)(arow + kf * 32);
        acc = __builtin_amdgcn_mfma_f32_16x16x32_f16(af, bfr[kf], acc, 0, 0, 0);
      }
      f16* obase = Vh + ((size_t)(b * C_DIM + ot * 16 + quad * 4)) * N_DIM + j0 + li;
#pragma unroll
      for (int r = 0; r < 4; r++) {
        float bb = bias[ot * 16 + quad * 4 + r];
        obase[(size_t)r * N_DIM] = (f16)(acc[r] + bb);
      }
    }
  }
}

// ---------------- fused attention ----------------
// grid (64,4): 64-query block, batch. 4 waves x 16 query-cols.
// JT=64 keys/tile, NT=64 tiles. DMA staging (global_load_lds, 16B), dbuf.
// LDS layouts (f16 units), all bank-even:
//   K: 64 rows x 512B; DMA span = 2 rows = 1024B, pair stride 528 f16 (1056B).
//      phys(r,k) = (r>>1)*528 + (r&1)*256 + k
//   V: 256 rows x 128B; span = 8 rows, group stride 528 f16.
//      phys(c,j) = (c>>3)*528 + (c&7)*64 + j
//   P (per wave): [16 i][64 j], row stride 80 f16 (160B).
#define JT 64
#define NT (N_DIM / JT)
#define KBUF 16896            // 32 pairs * 528
#define VBUF 16896            // 32 groups * 528
#define K0_OFF 0
#define K1_OFF 16896
#define V0_OFF 33792
#define V1_OFF 50688
#define P_OFF  67584
#define PSTR 80
#define SMEM_F16 72704        // 145408 B

__global__ __launch_bounds__(256, 1) void k_attn(const f16* __restrict__ Qh,
                                                 const f16* __restrict__ Kh,
                                                 const f16* __restrict__ Vh,
                                                 const float* __restrict__ x,
                                                 const float* __restrict__ gamma_p,
                                                 float* __restrict__ out) {
  __shared__ __align__(16) f16 smem[SMEM_F16];
  const int b = blockIdx.y;
  const int tid = threadIdx.x;
  const int w = tid >> 6, lane = tid & 63;
  const int quad = lane >> 4, li = lane & 15;
  const int ibase = blockIdx.x * 64 + w * 16;

  // Q fragments (B-operand: n = query col, k = channel)
  f16x8 qf[8];
  {
    const f16* qrow = Qh + (size_t)(b * N_DIM + ibase + li) * C_DIM + quad * 8;
#pragma unroll
    for (int kf = 0; kf < 8; kf++) qf[kf] = *(const f16x8*)(qrow + kf * 32);
  }
  const f16* Kb = Kh + (size_t)b * N_DIM * C_DIM;
  const f16* Vb = Vh + (size_t)b * C_DIM * N_DIM;
  f16* Pw = smem + P_OFF + w * 16 * PSTR;

  const float LOG2E = 1.4426950408889634f;
  float m = -3.0e38f, l = 0.0f;
  f32x4 acc[16];
#pragma unroll
  for (int ct = 0; ct < 16; ct++) acc[ct] = (f32x4){0.f, 0.f, 0.f, 0.f};

  // prologue: DMA tile 0 -> buf0
  {
    const f16* kg = Kb;
    const f16* vg = Vb;
#pragma unroll
    for (int it = 0; it < 8; it++) {
      int p = w * 8 + it;
      dma16(kg + (size_t)(2 * p + (lane >> 5)) * C_DIM + (lane & 31) * 8,
            smem + K0_OFF + p * 528);
      dma16(vg + (size_t)(p * 8 + (lane >> 3)) * N_DIM + (lane & 7) * 8,
            smem + V0_OFF + p * 528);
    }
  }
  __syncthreads();

  for (int t = 0; t < NT; t++) {
    const f16* Kc = smem + ((t & 1) ? K1_OFF : K0_OFF);
    const f16* Vc = smem + ((t & 1) ? V1_OFF : V0_OFF);

    // issue DMA for tile t+1 into the other buffer (drained at the barrier)
    if (t + 1 < NT) {
      f16* Kn = smem + ((t & 1) ? K0_OFF : K1_OFF);
      f16* Vn = smem + ((t & 1) ? V0_OFF : V1_OFF);
      const int jt = (t + 1) * JT;
      const f16* kg = Kb + (size_t)jt * C_DIM;
      const f16* vg = Vb + jt;
#pragma unroll
      for (int it = 0; it < 8; it++) {
        int p = w * 8 + it;
        dma16(kg + (size_t)(2 * p + (lane >> 5)) * C_DIM + (lane & 31) * 8,
              Kn + p * 528);
        dma16(vg + (size_t)(p * 8 + (lane >> 3)) * N_DIM + (lane & 7) * 8,
              Vn + p * 528);
      }
    }

    // ---- S^T: rows j (sub*16 + quad*4 + reg), cols i (lane&15) ----
    f32x4 s[4];
#pragma unroll
    for (int sub = 0; sub < 4; sub++) {
      f32x4 ss = {0.f, 0.f, 0.f, 0.f};
      const int r = sub * 16 + li;
      const f16* krow = Kc + (r >> 1) * 528 + (r & 1) * 256 + quad * 8;
#pragma unroll
      for (int kf = 0; kf < 8; kf++) {
        f16x8 kfr = *(const f16x8*)(krow + kf * 32);
        ss = __builtin_amdgcn_mfma_f32_16x16x32_f16(kfr, qf[kf], ss, 0, 0, 0);
      }
      s[sub] = ss;
    }

    // ---- online softmax (per query col li) ----
    float tm = -3.0e38f;
#pragma unroll
    for (int sub = 0; sub < 4; sub++)
      tm = fmaxf(tm, fmaxf(fmaxf(s[sub][0], s[sub][1]), fmaxf(s[sub][2], s[sub][3])));
    tm = fmaxf(tm, __shfl_xor(tm, 16));
    tm = fmaxf(tm, __shfl_xor(tm, 32));
    float nm = fmaxf(m, tm);
    float alpha = exp2f((m - nm) * LOG2E);
    m = nm;
    if (__any(alpha < 1.0f)) {      // wave-uniform skip when max unchanged
      l *= alpha;
#pragma unroll
      for (int ct = 0; ct < 16; ct++) {
        acc[ct][0] *= alpha; acc[ct][1] *= alpha;
        acc[ct][2] *= alpha; acc[ct][3] *= alpha;
      }
    }
#pragma unroll
    for (int sub = 0; sub < 4; sub++) {
      float p0 = exp2f((s[sub][0] - m) * LOG2E);
      float p1 = exp2f((s[sub][1] - m) * LOG2E);
      float p2 = exp2f((s[sub][2] - m) * LOG2E);
      float p3 = exp2f((s[sub][3] - m) * LOG2E);
      l += (p0 + p1) + (p2 + p3);
      *(f16x4*)(Pw + li * PSTR + sub * 16 + quad * 4) =
          (f16x4){(f16)p0, (f16)p1, (f16)p2, (f16)p3};
    }

    // ---- PV: O^T[c][i] += V[c][j] P^T[j][i] (k = j, two 32-chunks) ----
    f16x8 pf0 = *(const f16x8*)(Pw + li * PSTR + quad * 8);
    f16x8 pf1 = *(const f16x8*)(Pw + li * PSTR + 32 + quad * 8);
#pragma unroll
    for (int ct = 0; ct < 16; ct++) {
      const f16* vrow = Vc + (ct * 2 + (li >> 3)) * 528 + (li & 7) * 64 + quad * 8;
      f16x8 v0 = *(const f16x8*)(vrow);
      f16x8 v1 = *(const f16x8*)(vrow + 32);
      acc[ct] = __builtin_amdgcn_mfma_f32_16x16x32_f16(v0, pf0, acc[ct], 0, 0, 0);
      acc[ct] = __builtin_amdgcn_mfma_f32_16x16x32_f16(v1, pf1, acc[ct], 0, 0, 0);
    }

    __syncthreads();   // waits readers of current bufs AND drains next-tile DMA
  }

  l += __shfl_xor(l, 16);
  l += __shfl_xor(l, 32);
  const float scale = gamma_p[0] / l;

  const float* xb = x + (size_t)b * C_DIM * N_DIM;
  float* ob = out + (size_t)b * C_DIM * N_DIM;
  const int icol = ibase + li;
#pragma unroll
  for (int ct = 0; ct < 16; ct++) {
#pragma unroll
    for (int r = 0; r < 4; r++) {
      size_t off = (size_t)(ct * 16 + quad * 4 + r) * N_DIM + icol;
      ob[off] = acc[ct][r] * scale + xb[off];
    }
  }
}

extern "C" void kernel_launch(void* const* d_in, const int* in_sizes, int n_in,
                              void* d_out, int out_size, void* d_ws, size_t ws_size,
                              hipStream_t stream) {
  const float* x     = (const float*)d_in[0];
  const float* Wq    = (const float*)d_in[1];
  const float* bq    = (const float*)d_in[2];
  const float* Wk    = (const float*)d_in[3];
  const float* bk    = (const float*)d_in[4];
  const float* Wv    = (const float*)d_in[5];
  const float* bv    = (const float*)d_in[6];
  const float* gamma = (const float*)d_in[7];
  float* out = (float*)d_out;

  // workspace: xs 8MB | Qh 8MB | Kh 8MB | Vh 8MB | Wh 384KB  (~32.4 MB)
  char* ws = (char*)d_ws;
  f16* xs = (f16*)(ws);
  f16* Qh = (f16*)(ws + (size_t)8  * 1024 * 1024);
  f16* Kh = (f16*)(ws + (size_t)16 * 1024 * 1024);
  f16* Vh = (f16*)(ws + (size_t)24 * 1024 * 1024);
  f16* Wh = (f16*)(ws + (size_t)32 * 1024 * 1024);

  k_prep_xs<<<dim3(64, 4, 4), 256, 0, stream>>>(x, xs);
  k_cast_w<<<dim3(768), 256, 0, stream>>>(Wq, Wk, Wv, Wh);
  k_proj<<<dim3(256, 3), 256, 0, stream>>>(xs, Wh, bq, bk, bv, Qh, Kh, Vh);
  k_attn<<<dim3(64, 4), 256, 0, stream>>>(Qh, Kh, Vh, x, gamma, out);
}